// Round 4
// baseline (117.690 us; speedup 1.0000x reference)
//
#include <hip/hip_runtime.h>
#include <math.h>

// Round-15 = round-14 resubmitted verbatim (round-3 bench died in the
// container broker, not the kernel: no compile error, no counters, and the
// diff contained nothing capable of killing a container). Keeping the
// source identical preserves the A/B chain.
//
// Round-14 rationale: r13 post-mortem: VALU-issue product (dur*busy) =
// 38.6 us-units -> at 100% busy the inst count floors us at ~38.6us; the
// 20% idle is LDS latency (16 b64 reads ph2 + 8 dynamic reads ph3)
// unbatchable at VGPR=48. This round: LDS payload compressed to t.
//  (a) LDS = [16][256] float (16KB): 10 blocks/CU -> LDS wave cap 40/CU;
//      occupancy now VGPR-bound only. Row stride 1024B == 0 mod 128 ->
//      bank = f(lane) only -> conflict-free even for dynamic rows.
//  (b) t[16] ALSO kept in registers (static indices only) -> phase 2 does
//      ZERO ds_reads: ix = FADD(x1, FMUL(t, ex)) recomputed from identical
//      bits (ex/ey are deterministic FSUBs of unchanged corner regs) ->
//      bit-identical keys. Key loop reordered intersections-first so t[]
//      dies before pk[] peaks (peak live ~58 regs, no AGPR shuttling).
//  (c) phase 3: one ds_read_b32 (t) + 3-cndmask e1-trees for (x1,y1,xn,yn)
//      reconstruct; corner path keeps the 3-level tree. DS ops 40 -> 24.
// Sort net unchanged (keys unique -> network order == extraction order).
// FROZEN (bit-critical): atan2f/cosf/sinf + __f*_rn corner chain, mask
// ratios, masked sx/sy sum order, centroid FDIV, key function, cross order.

#define FMUL __fmul_rn
#define FADD __fadd_rn
#define FSUB __fsub_rn
#define FDIV __fdiv_rn

__device__ __forceinline__ float rcpf_(float x) { return __builtin_amdgcn_rcpf(x); }

// compare-exchange on packed keys: min -> pk[A], max -> pk[B]
#define CE(A,B) do { unsigned _x = pk[A], _y = pk[B]; \
                     pk[A] = _x < _y ? _x : _y; pk[B] = _x < _y ? _y : _x; } while (0)

// Batcher odd-even mergesort of pk[o..o+7], 19 CE
#define SORT8(o) do { \
    CE(o+0,o+1); CE(o+2,o+3); CE(o+0,o+2); CE(o+1,o+3); CE(o+1,o+2); \
    CE(o+4,o+5); CE(o+6,o+7); CE(o+4,o+6); CE(o+5,o+7); CE(o+5,o+6); \
    CE(o+0,o+4); CE(o+1,o+5); CE(o+2,o+6); CE(o+3,o+7); \
    CE(o+2,o+4); CE(o+3,o+5); \
    CE(o+1,o+2); CE(o+3,o+4); CE(o+5,o+6); } while (0)

// pk[0..7] sorted asc, pk[o..o+7] sorted asc ->
// pk[0..7] = lowest 8 of the 16, sorted (half-cleaner + bitonic-8).
#define MERGE_LOW8(o) do { \
    CE(0,o+7); CE(1,o+6); CE(2,o+5); CE(3,o+4); \
    CE(4,o+3); CE(5,o+2); CE(6,o+1); CE(7,o+0); \
    CE(0,4); CE(1,5); CE(2,6); CE(3,7); \
    CE(0,2); CE(1,3); CE(4,6); CE(5,7); \
    CE(0,1); CE(2,3); CE(4,5); CE(6,7); } while (0)

// Reconstruct/select payload for dynamic slot in [0,24):
//   slot>=8: intersection, t from LDS (pre-read into TQ), e1-trees.
//   slot<8 : corner via 3-level cndmask tree.
// All array indices static -> registers only.
#define GATHER(SLOT, TQ, OUTX, OUTY) do {                                   \
    unsigned _sl = (SLOT);                                                  \
    unsigned _sb = _sl - 8u;               /* garbage if corner; gated */   \
    bool _e0 = (_sb & 4u) != 0u, _e1 = (_sb & 8u) != 0u;                    \
    float _x1 = _e1 ? (_e0 ? c1x[3] : c1x[2]) : (_e0 ? c1x[1] : c1x[0]);    \
    float _y1 = _e1 ? (_e0 ? c1y[3] : c1y[2]) : (_e0 ? c1y[1] : c1y[0]);    \
    float _xn = _e1 ? (_e0 ? c1x[0] : c1x[3]) : (_e0 ? c1x[2] : c1x[1]);    \
    float _yn = _e1 ? (_e0 ? c1y[0] : c1y[3]) : (_e0 ? c1y[2] : c1y[1]);    \
    float _ix = FADD(_x1, FMUL((TQ), FSUB(_xn, _x1)));                      \
    float _iy = FADD(_y1, FMUL((TQ), FSUB(_yn, _y1)));                      \
    unsigned _b = _sl & 7u;                                                 \
    bool _b0 = (_b & 1u) != 0u, _b1 = (_b & 2u) != 0u, _b2 = (_b & 4u) != 0u;\
    float _a0x = _b0 ? c1x[1] : c1x[0], _a0y = _b0 ? c1y[1] : c1y[0];       \
    float _a1x = _b0 ? c1x[3] : c1x[2], _a1y = _b0 ? c1y[3] : c1y[2];       \
    float _a2x = _b0 ? c2x[1] : c2x[0], _a2y = _b0 ? c2y[1] : c2y[0];       \
    float _a3x = _b0 ? c2x[3] : c2x[2], _a3y = _b0 ? c2y[3] : c2y[2];       \
    float _m0x = _b1 ? _a1x : _a0x, _m0y = _b1 ? _a1y : _a0y;               \
    float _m1x = _b1 ? _a3x : _a2x, _m1y = _b1 ? _a3y : _a2y;               \
    float _cx = _b2 ? _m1x : _m0x, _cy = _b2 ? _m1y : _m0y;                 \
    bool _isC = _sl < 8u;                                                   \
    (OUTX) = _isC ? _cx : _ix;                                              \
    (OUTY) = _isC ? _cy : _iy;                                              \
} while (0)

__global__
__attribute__((amdgpu_flat_work_group_size(256, 256), amdgpu_waves_per_eu(1)))
void riou_kernel(const float* __restrict__ pred,
                 const float* __restrict__ tgt,
                 float* __restrict__ out, int n)
{
    // t-parameter store only: 16KB/block -> 10 blocks/CU (LDS cap 40 waves).
    __shared__ float tlds[16][256];
    const int tid = threadIdx.x;
    int i = blockIdx.x * blockDim.x + tid;
    if (i >= n) return;

    const float2* p2 = (const float2*)(pred + 6 * (size_t)i);
    const float2* q2 = (const float2*)(tgt  + 6 * (size_t)i);
    float2 pa = p2[0], pb = p2[1], pc2 = p2[2];
    float2 qa = q2[0], qb = q2[1], qc2 = q2[2];
    const float px = pa.x, py = pa.y, pw = pb.x, ph = pb.y;
    const float qx = qa.x, qy = qa.y, qw = qb.x, qh = qb.y;

    // bit-critical transcendental sequence — DO NOT substitute identities
    float rad1 = atan2f(pc2.x, pc2.y);
    float cA = cosf(rad1), sA = sinf(rad1);
    float rad2 = atan2f(qc2.x, qc2.y);
    float cB = cosf(rad2), sB = sinf(rad2);

    const float ddx[4] = {0.5f, -0.5f, -0.5f, 0.5f};
    const float ddy[4] = {0.5f, 0.5f, -0.5f, -0.5f};
    float c1x[4], c1y[4], c2x[4], c2y[4];
#pragma unroll
    for (int j = 0; j < 4; j++) {
        float cx = FMUL(ddx[j], pw), cy = FMUL(ddy[j], ph);
        c1x[j] = FADD(FSUB(FMUL(cx, cA), FMUL(cy, sA)), px);
        c1y[j] = FADD(FADD(FMUL(cx, sA), FMUL(cy, cA)), py);
        float dx2 = FMUL(ddx[j], qw), dy2 = FMUL(ddy[j], qh);
        c2x[j] = FADD(FSUB(FMUL(dx2, cB), FMUL(dy2, sB)), qx);
        c2y[j] = FADD(FADD(FMUL(dx2, sB), FMUL(dy2, cB)), qy);
    }

    // enclosing-box diagonal + center distance
    float minx = c1x[0], maxx = c1x[0], miny = c1y[0], maxy = c1y[0];
#pragma unroll
    for (int j = 1; j < 4; j++) {
        minx = fminf(minx, c1x[j]); maxx = fmaxf(maxx, c1x[j]);
        miny = fminf(miny, c1y[j]); maxy = fmaxf(maxy, c1y[j]);
    }
#pragma unroll
    for (int j = 0; j < 4; j++) {
        minx = fminf(minx, c2x[j]); maxx = fmaxf(maxx, c2x[j]);
        miny = fminf(miny, c2y[j]); maxy = fmaxf(maxy, c2y[j]);
    }
    float wcb = FSUB(maxx, minx), hcb = FSUB(maxy, miny);
    float c2d = FADD(FMUL(wcb, wcb), FMUL(hcb, hcb));
    float dxc = FSUB(px, qx), dyc = FSUB(py, qy);
    float d2 = FADD(FMUL(dxc, dxc), FMUL(dyc, dyc));

    // ---- phase 1: 24 candidate slots, mask bits + masked sums ----
    unsigned mbits = 0;
    float sx = 0.0f, sy = 0.0f;
    const float eps = 1e-6f;
    const float hieps = 1.0f + 1e-6f;

    // slots 0-3: c1 corners inside c2 (payload stays in regs)
    {
        float ax = c2x[0], ay = c2y[0];
        float abx = FSUB(c2x[1], ax), aby = FSUB(c2y[1], ay);
        float adx = FSUB(c2x[3], ax), ady = FSUB(c2y[3], ay);
        float rab = rcpf_(FADD(FMUL(abx, abx), FMUL(aby, aby)));
        float rad = rcpf_(FADD(FMUL(adx, adx), FMUL(ady, ady)));
#pragma unroll
        for (int j = 0; j < 4; j++) {
            float amx = FSUB(c1x[j], ax), amy = FSUB(c1y[j], ay);
            float pab = FMUL(FADD(FMUL(abx, amx), FMUL(aby, amy)), rab);
            float pad = FMUL(FADD(FMUL(adx, amx), FMUL(ady, amy)), rad);
            int m = (pab > -eps) & (pab < hieps) & (pad > -eps) & (pad < hieps);
            mbits |= (unsigned)m << j;
            sx = FADD(sx, m ? c1x[j] : 0.0f);
            sy = FADD(sy, m ? c1y[j] : 0.0f);
        }
    }
    // slots 4-7: c2 corners inside c1 (payload stays in regs)
    {
        float ax = c1x[0], ay = c1y[0];
        float abx = FSUB(c1x[1], ax), aby = FSUB(c1y[1], ay);
        float adx = FSUB(c1x[3], ax), ady = FSUB(c1y[3], ay);
        float rab = rcpf_(FADD(FMUL(abx, abx), FMUL(aby, aby)));
        float rad = rcpf_(FADD(FMUL(adx, adx), FMUL(ady, ady)));
#pragma unroll
        for (int j = 0; j < 4; j++) {
            float amx = FSUB(c2x[j], ax), amy = FSUB(c2y[j], ay);
            float pab = FMUL(FADD(FMUL(abx, amx), FMUL(aby, amy)), rab);
            float pad = FMUL(FADD(FMUL(adx, amx), FMUL(ady, amy)), rad);
            int m = (pab > -eps) & (pab < hieps) & (pad > -eps) & (pad < hieps);
            mbits |= (unsigned)m << (4 + j);
            sx = FADD(sx, m ? c2x[j] : 0.0f);
            sy = FADD(sy, m ? c2y[j] : 0.0f);
        }
    }
    // slots 8-23: edge intersections; den_u = -den_t exactly -> one rcp.
    // t -> LDS (b32) AND t -> register array tv[] (static indices only).
    float fex[4], fey[4];
#pragma unroll
    for (int e2 = 0; e2 < 4; e2++) {
        fex[e2] = FSUB(c2x[(e2 + 1) & 3], c2x[e2]);
        fey[e2] = FSUB(c2y[(e2 + 1) & 3], c2y[e2]);
    }
    float tv[16];
#pragma unroll
    for (int e1 = 0; e1 < 4; e1++) {
        float x1 = c1x[e1], y1 = c1y[e1];
        float ex = FSUB(c1x[(e1 + 1) & 3], x1), ey = FSUB(c1y[(e1 + 1) & 3], y1);
#pragma unroll
        for (int e2 = 0; e2 < 4; e2++) {
            float dx31 = FSUB(c2x[e2], x1), dy31 = FSUB(c2y[e2], y1);
            float num_t = FSUB(FMUL(ex, dy31), FMUL(ey, dx31));
            float den_t = FSUB(FMUL(ey, fex[e2]), FMUL(ex, fey[e2]));
            float rd = rcpf_(den_t);          // den==0 -> inf -> masked below
            float tq = FMUL(num_t, rd);
            float num_u = FSUB(FMUL(fey[e2], dx31), FMUL(fex[e2], dy31));
            float uq = FMUL(num_u, rd);       // == -u exactly
            int m = (tq > 0.0f) & (tq < 1.0f) & (uq < 0.0f) & (uq > -1.0f);
            float ix = FADD(x1, FMUL(tq, ex));   // garbage if masked; gated
            float iy = FADD(y1, FMUL(tq, ey));
            int s = 4 * e1 + e2;
            tv[s] = tq;
            tlds[s][tid] = tq;
            mbits |= (unsigned)m << (8 + s);
            sx = FADD(sx, m ? ix : 0.0f);
            sy = FADD(sy, m ? iy : 0.0f);
        }
    }

    int k = __popc(mbits);

    // centroid (IEEE div: feeds every recentered coordinate — bit-frozen)
    float kk = (float)(k > 0 ? k : 1);
    float mx = FDIV(sx, kk), my = FDIV(sy, kk);

    // ---- phase 2: u32 packed keys (27-bit angle | 5-bit slot).
    // Intersections FIRST (consumes tv[] -> dies before pk[] peaks);
    // ix,iy recomputed from t with identical bits (same FMUL/FADD inputs).
    unsigned pk[24];
#pragma unroll
    for (int j = 8; j < 24; j++) {
        const int s = j - 8, e1 = s >> 2;
        float x1 = c1x[e1], y1 = c1y[e1];
        float ex = FSUB(c1x[(e1 + 1) & 3], x1), ey = FSUB(c1y[(e1 + 1) & 3], y1);
        float rx = FADD(x1, FMUL(tv[s], ex));
        float ry = FADD(y1, FMUL(tv[s], ey));
        int m = (mbits >> j) & 1u;
        float wx2 = FSUB(rx, mx);
        float wy2 = FSUB(ry, my);
        float dsum = FADD(fabsf(wx2), fabsf(wy2));
        float rs = (dsum > 0.0f) ? FMUL(wx2, rcpf_(dsum)) : 1.0f;
        float keyf = copysignf(FSUB(1.0f, rs), wy2);   // monotone in atan2
        unsigned sb = __float_as_uint(keyf);
        unsigned u = sb ^ (unsigned)(((int)sb >> 31) | (int)0x80000000);
        pk[j] = m ? ((u & 0xFFFFFFE0u) | (unsigned)j)
                  : (0xFFFFFFE0u | (unsigned)j);       // masked: sorts last
    }
#pragma unroll
    for (int j = 0; j < 8; j++) {
        float rx = (j < 4) ? c1x[j] : c2x[j - 4];
        float ry = (j < 4) ? c1y[j] : c2y[j - 4];
        int m = (mbits >> j) & 1u;
        float wx2 = FSUB(rx, mx);
        float wy2 = FSUB(ry, my);
        float dsum = FADD(fabsf(wx2), fabsf(wy2));
        float rs = (dsum > 0.0f) ? FMUL(wx2, rcpf_(dsum)) : 1.0f;
        float keyf = copysignf(FSUB(1.0f, rs), wy2);
        unsigned sb = __float_as_uint(keyf);
        unsigned u = sb ^ (unsigned)(((int)sb >> 31) | (int)0x80000000);
        pk[j] = m ? ((u & 0xFFFFFFE0u) | (unsigned)j)
                  : (0xFFFFFFE0u | (unsigned)j);
    }

    // ---- phase 2.5: partial sort network — lowest 8 sorted into pk[0..7].
    // 97 CE, 2 VALU each; keys unique -> output order == extraction order.
    SORT8(0);
    SORT8(8);
    SORT8(16);
    MERGE_LOW8(8);
    MERGE_LOW8(16);

    // ---- phase 3: gather payload for the 8 smallest, recenter (exact FSUB).
    float gxv[8], gyv[8];
#pragma unroll
    for (int s = 0; s < 8; s++) {
        unsigned slot = pk[s] & 31u;         // in [0,24)
        int ls = (int)slot - 8;
        ls = ls < 0 ? 0 : ls;
        float tq = tlds[ls][tid];            // dynamic row: conflict-free
        float rxv, ryv;
        GATHER(slot, tq, rxv, ryv);
        gxv[s] = FSUB(rxv, mx);
        gyv[s] = FSUB(ryv, my);
    }

    float firstx = 0.0f, firsty = 0.0f, prevx = 0.0f, prevy = 0.0f;
    float crs = 0.0f;
#pragma unroll
    for (int s = 0; s < 8; s++) {
        bool act = s < k;                  // inactive pass: payload -> prev
        float bx = act ? gxv[s] : prevx;
        float by = act ? gyv[s] : prevy;
        if (s == 0) { firstx = bx; firsty = by; }
        else {
            // inactive: cross(prev,prev) = exact IEEE 0 (identical products)
            crs = FADD(crs, FSUB(FMUL(prevx, by), FMUL(prevy, bx)));
        }
        prevx = bx; prevy = by;
    }
    // rare tail: noise masks can push k past the geometric bound of 8.
    // Leftovers in pk[8..23] all exceed pk[7] -> successive minima continue
    // the ascending order; keys unique -> sentinel removal removes one.
    if (k > 8) {
        for (int s = 8; s < k; s++) {
            unsigned mn = pk[8];
#pragma unroll
            for (int j = 9; j < 24; j++) mn = (pk[j] < mn) ? pk[j] : mn;
            unsigned slot = mn & 31u;
            int ls = (int)slot - 8;
            ls = ls < 0 ? 0 : ls;
            float tq = tlds[ls][tid];
            float rxv, ryv;
            GATHER(slot, tq, rxv, ryv);
            float bx = FSUB(rxv, mx);
            float by = FSUB(ryv, my);
            crs = FADD(crs, FSUB(FMUL(prevx, by), FMUL(prevy, bx)));
            prevx = bx; prevy = by;
#pragma unroll
            for (int j = 8; j < 24; j++) if (pk[j] == mn) pk[j] = 0xFFFFFFFFu;
        }
    }
    // close the ring
    crs = FADD(crs, FSUB(FMUL(prevx, firsty), FMUL(prevy, firstx)));
    float inter = FMUL(0.5f, fabsf(crs));

    float area1 = FMUL(pw, ph), area2 = FMUL(qw, qh);
    float uni = FSUB(FADD(area1, area2), inter);
    float iou = FMUL(inter, rcpf_(uni));

    out[i] = FADD(FSUB(1.0f, iou), FMUL(d2, rcpf_(c2d)));
}

extern "C" void kernel_launch(void* const* d_in, const int* in_sizes, int n_in,
                              void* d_out, int out_size, void* d_ws, size_t ws_size,
                              hipStream_t stream) {
    const float* pred = (const float*)d_in[0];
    const float* tgt  = (const float*)d_in[1];
    float* out = (float*)d_out;
    int n = in_sizes[0] / 6;
    int block = 256;
    int grid = (n + block - 1) / block;
    riou_kernel<<<grid, block, 0, stream>>>(pred, tgt, out, n);
}

// Round 5
// 114.292 us; speedup vs baseline: 1.0297x; 1.0297x over previous
//
#include <hip/hip_runtime.h>
#include <math.h>

// Round-16: r14 post-mortem: trading DS ops for VALU regressed (product
// 38.6 -> 42.2 us-units; dur 48.2 -> 51.5). Revised model: DS ops issue on
// the LDS pipe (free for VALU); their only cost is latency. So: keep the
// minimum-VALU dataflow (r13: float2 payload in LDS, keys READ not
// recomputed) and hide DS latency with BATCHED reads (ILP), not recompute.
//  - phase 2: 16 ds_read_b64 in two batches of 8, corner-key VALU placed
//    between issue and use (one lgkmcnt wait per 8 reads).
//  - phase 3: all 8 dynamic gathers issued as one batch into vi[8]; the
//    corner cndmask tree + ring walk consume afterwards (gxv/gyv gone).
//  - LDS = [16][256] float2 = 32KB (intersections only; corners in regs).
//    Row stride 2048B == 0 mod 128 -> bank = f(lane) only -> conflict-free
//    even for dynamic rows; per-thread column -> no barriers.
// Arithmetic is bitwise r13 (passed at absmax 2^-8).
// FROZEN (bit-critical): atan2f/cosf/sinf + __f*_rn corner chain, mask
// ratios, masked sx/sy sum order, centroid FDIV, key function, cross order.

#define FMUL __fmul_rn
#define FADD __fadd_rn
#define FSUB __fsub_rn
#define FDIV __fdiv_rn

__device__ __forceinline__ float rcpf_(float x) { return __builtin_amdgcn_rcpf(x); }

// compare-exchange on packed keys: min -> pk[A], max -> pk[B]
#define CE(A,B) do { unsigned _x = pk[A], _y = pk[B]; \
                     pk[A] = _x < _y ? _x : _y; pk[B] = _x < _y ? _y : _x; } while (0)

// Batcher odd-even mergesort of pk[o..o+7], 19 CE
#define SORT8(o) do { \
    CE(o+0,o+1); CE(o+2,o+3); CE(o+0,o+2); CE(o+1,o+3); CE(o+1,o+2); \
    CE(o+4,o+5); CE(o+6,o+7); CE(o+4,o+6); CE(o+5,o+7); CE(o+5,o+6); \
    CE(o+0,o+4); CE(o+1,o+5); CE(o+2,o+6); CE(o+3,o+7); \
    CE(o+2,o+4); CE(o+3,o+5); \
    CE(o+1,o+2); CE(o+3,o+4); CE(o+5,o+6); } while (0)

// pk[0..7] sorted asc, pk[o..o+7] sorted asc ->
// pk[0..7] = lowest 8 of the 16, sorted (half-cleaner + bitonic-8).
#define MERGE_LOW8(o) do { \
    CE(0,o+7); CE(1,o+6); CE(2,o+5); CE(3,o+4); \
    CE(4,o+3); CE(5,o+2); CE(6,o+1); CE(7,o+0); \
    CE(0,4); CE(1,5); CE(2,6); CE(3,7); \
    CE(0,2); CE(1,3); CE(4,6); CE(5,7); \
    CE(0,1); CE(2,3); CE(4,5); CE(6,7); } while (0)

// u32 packed key (27-bit diamond-angle | 5-bit slot), monotone in atan2.
#define MAKEKEY(J, WX, WY, M, DST) do {                                     \
    float _dsum = FADD(fabsf(WX), fabsf(WY));                               \
    float _rs = (_dsum > 0.0f) ? FMUL((WX), rcpf_(_dsum)) : 1.0f;           \
    float _keyf = copysignf(FSUB(1.0f, _rs), (WY));                         \
    unsigned _sbk = __float_as_uint(_keyf);                                 \
    unsigned _u = _sbk ^ (unsigned)(((int)_sbk >> 31) | (int)0x80000000);   \
    (DST) = (M) ? ((_u & 0xFFFFFFE0u) | (unsigned)(J))                      \
                : (0xFFFFFFE0u | (unsigned)(J));                            \
} while (0)

// Payload select for dynamic slot: slot>=8 -> VI (already read from LDS);
// slot<8 -> 3-level cndmask tree over corner regs. Static indices only.
#define SELPAY(SLOT, VI, OUTX, OUTY) do {                                   \
    unsigned _b = (SLOT) & 7u;                                              \
    bool _b0 = (_b & 1u) != 0u, _b1 = (_b & 2u) != 0u, _b2 = (_b & 4u) != 0u;\
    float _a0x = _b0 ? c1x[1] : c1x[0], _a0y = _b0 ? c1y[1] : c1y[0];       \
    float _a1x = _b0 ? c1x[3] : c1x[2], _a1y = _b0 ? c1y[3] : c1y[2];       \
    float _a2x = _b0 ? c2x[1] : c2x[0], _a2y = _b0 ? c2y[1] : c2y[0];       \
    float _a3x = _b0 ? c2x[3] : c2x[2], _a3y = _b0 ? c2y[3] : c2y[2];       \
    float _m0x = _b1 ? _a1x : _a0x, _m0y = _b1 ? _a1y : _a0y;               \
    float _m1x = _b1 ? _a3x : _a2x, _m1y = _b1 ? _a3y : _a2y;               \
    float _cx = _b2 ? _m1x : _m0x, _cy = _b2 ? _m1y : _m0y;                 \
    bool _isC = (SLOT) < 8u;                                                \
    (OUTX) = _isC ? _cx : (VI).x;                                           \
    (OUTY) = _isC ? _cy : (VI).y;                                           \
} while (0)

__global__
__attribute__((amdgpu_flat_work_group_size(256, 256), amdgpu_waves_per_eu(1)))
void riou_kernel(const float* __restrict__ pred,
                 const float* __restrict__ tgt,
                 float* __restrict__ out, int n)
{
    __shared__ float2 vlds[16][256];
    const int tid = threadIdx.x;
    int i = blockIdx.x * blockDim.x + tid;
    if (i >= n) return;

    const float2* p2 = (const float2*)(pred + 6 * (size_t)i);
    const float2* q2 = (const float2*)(tgt  + 6 * (size_t)i);
    float2 pa = p2[0], pb = p2[1], pc2 = p2[2];
    float2 qa = q2[0], qb = q2[1], qc2 = q2[2];
    const float px = pa.x, py = pa.y, pw = pb.x, ph = pb.y;
    const float qx = qa.x, qy = qa.y, qw = qb.x, qh = qb.y;

    // bit-critical transcendental sequence — DO NOT substitute identities
    float rad1 = atan2f(pc2.x, pc2.y);
    float cA = cosf(rad1), sA = sinf(rad1);
    float rad2 = atan2f(qc2.x, qc2.y);
    float cB = cosf(rad2), sB = sinf(rad2);

    const float ddx[4] = {0.5f, -0.5f, -0.5f, 0.5f};
    const float ddy[4] = {0.5f, 0.5f, -0.5f, -0.5f};
    float c1x[4], c1y[4], c2x[4], c2y[4];
#pragma unroll
    for (int j = 0; j < 4; j++) {
        float cx = FMUL(ddx[j], pw), cy = FMUL(ddy[j], ph);
        c1x[j] = FADD(FSUB(FMUL(cx, cA), FMUL(cy, sA)), px);
        c1y[j] = FADD(FADD(FMUL(cx, sA), FMUL(cy, cA)), py);
        float dx2 = FMUL(ddx[j], qw), dy2 = FMUL(ddy[j], qh);
        c2x[j] = FADD(FSUB(FMUL(dx2, cB), FMUL(dy2, sB)), qx);
        c2y[j] = FADD(FADD(FMUL(dx2, sB), FMUL(dy2, cB)), qy);
    }

    // enclosing-box diagonal + center distance
    float minx = c1x[0], maxx = c1x[0], miny = c1y[0], maxy = c1y[0];
#pragma unroll
    for (int j = 1; j < 4; j++) {
        minx = fminf(minx, c1x[j]); maxx = fmaxf(maxx, c1x[j]);
        miny = fminf(miny, c1y[j]); maxy = fmaxf(maxy, c1y[j]);
    }
#pragma unroll
    for (int j = 0; j < 4; j++) {
        minx = fminf(minx, c2x[j]); maxx = fmaxf(maxx, c2x[j]);
        miny = fminf(miny, c2y[j]); maxy = fmaxf(maxy, c2y[j]);
    }
    float wcb = FSUB(maxx, minx), hcb = FSUB(maxy, miny);
    float c2d = FADD(FMUL(wcb, wcb), FMUL(hcb, hcb));
    float dxc = FSUB(px, qx), dyc = FSUB(py, qy);
    float d2 = FADD(FMUL(dxc, dxc), FMUL(dyc, dyc));

    // ---- phase 1: 24 candidate slots, mask bits + masked sums ----
    unsigned mbits = 0;
    float sx = 0.0f, sy = 0.0f;
    const float eps = 1e-6f;
    const float hieps = 1.0f + 1e-6f;

    // slots 0-3: c1 corners inside c2 (payload stays in regs)
    {
        float ax = c2x[0], ay = c2y[0];
        float abx = FSUB(c2x[1], ax), aby = FSUB(c2y[1], ay);
        float adx = FSUB(c2x[3], ax), ady = FSUB(c2y[3], ay);
        float rab = rcpf_(FADD(FMUL(abx, abx), FMUL(aby, aby)));
        float rad = rcpf_(FADD(FMUL(adx, adx), FMUL(ady, ady)));
#pragma unroll
        for (int j = 0; j < 4; j++) {
            float amx = FSUB(c1x[j], ax), amy = FSUB(c1y[j], ay);
            float pab = FMUL(FADD(FMUL(abx, amx), FMUL(aby, amy)), rab);
            float pad = FMUL(FADD(FMUL(adx, amx), FMUL(ady, amy)), rad);
            int m = (pab > -eps) & (pab < hieps) & (pad > -eps) & (pad < hieps);
            mbits |= (unsigned)m << j;
            sx = FADD(sx, m ? c1x[j] : 0.0f);
            sy = FADD(sy, m ? c1y[j] : 0.0f);
        }
    }
    // slots 4-7: c2 corners inside c1 (payload stays in regs)
    {
        float ax = c1x[0], ay = c1y[0];
        float abx = FSUB(c1x[1], ax), aby = FSUB(c1y[1], ay);
        float adx = FSUB(c1x[3], ax), ady = FSUB(c1y[3], ay);
        float rab = rcpf_(FADD(FMUL(abx, abx), FMUL(aby, aby)));
        float rad = rcpf_(FADD(FMUL(adx, adx), FMUL(ady, ady)));
#pragma unroll
        for (int j = 0; j < 4; j++) {
            float amx = FSUB(c2x[j], ax), amy = FSUB(c2y[j], ay);
            float pab = FMUL(FADD(FMUL(abx, amx), FMUL(aby, amy)), rab);
            float pad = FMUL(FADD(FMUL(adx, amx), FMUL(ady, amy)), rad);
            int m = (pab > -eps) & (pab < hieps) & (pad > -eps) & (pad < hieps);
            mbits |= (unsigned)m << (4 + j);
            sx = FADD(sx, m ? c2x[j] : 0.0f);
            sy = FADD(sy, m ? c2y[j] : 0.0f);
        }
    }
    // slots 8-23: edge intersections; den_u = -den_t exactly -> one rcp.
    // RAW (ix,iy) -> LDS row (slot-8). Garbage if masked; never selected.
    float fex[4], fey[4];
#pragma unroll
    for (int e2 = 0; e2 < 4; e2++) {
        fex[e2] = FSUB(c2x[(e2 + 1) & 3], c2x[e2]);
        fey[e2] = FSUB(c2y[(e2 + 1) & 3], c2y[e2]);
    }
#pragma unroll
    for (int e1 = 0; e1 < 4; e1++) {
        float x1 = c1x[e1], y1 = c1y[e1];
        float ex = FSUB(c1x[(e1 + 1) & 3], x1), ey = FSUB(c1y[(e1 + 1) & 3], y1);
#pragma unroll
        for (int e2 = 0; e2 < 4; e2++) {
            float dx31 = FSUB(c2x[e2], x1), dy31 = FSUB(c2y[e2], y1);
            float num_t = FSUB(FMUL(ex, dy31), FMUL(ey, dx31));
            float den_t = FSUB(FMUL(ey, fex[e2]), FMUL(ex, fey[e2]));
            float rd = rcpf_(den_t);          // den==0 -> inf -> masked below
            float tq = FMUL(num_t, rd);
            float num_u = FSUB(FMUL(fey[e2], dx31), FMUL(fex[e2], dy31));
            float uq = FMUL(num_u, rd);       // == -u exactly
            int m = (tq > 0.0f) & (tq < 1.0f) & (uq < 0.0f) & (uq > -1.0f);
            float ix = FADD(x1, FMUL(tq, ex));   // garbage if masked; gated
            float iy = FADD(y1, FMUL(tq, ey));
            int s = 4 * e1 + e2;                 // LDS row (slot - 8)
            vlds[s][tid] = make_float2(ix, iy);
            mbits |= (unsigned)m << (8 + s);
            sx = FADD(sx, m ? ix : 0.0f);
            sy = FADD(sy, m ? iy : 0.0f);
        }
    }

    int k = __popc(mbits);

    // centroid (IEEE div: feeds every recentered coordinate — bit-frozen)
    float kk = (float)(k > 0 ? k : 1);
    float mx = FDIV(sx, kk), my = FDIV(sy, kk);

    // ---- phase 2: keys. LDS reads in two batches of 8 (static row ->
    // immediate offsets, one lgkmcnt per batch); corner keys (pure VALU)
    // computed while batch A is in flight.
    unsigned pk[24];
    float2 va[8];
#pragma unroll
    for (int j = 0; j < 8; j++) va[j] = vlds[j][tid];        // slots 8..15
#pragma unroll
    for (int j = 0; j < 8; j++) {                            // corners
        float rx = (j < 4) ? c1x[j] : c2x[j - 4];
        float ry = (j < 4) ? c1y[j] : c2y[j - 4];
        int m = (mbits >> j) & 1u;
        float wx2 = FSUB(rx, mx);
        float wy2 = FSUB(ry, my);
        MAKEKEY(j, wx2, wy2, m, pk[j]);
    }
#pragma unroll
    for (int j = 8; j < 16; j++) {                           // slots 8..15
        int m = (mbits >> j) & 1u;
        float wx2 = FSUB(va[j - 8].x, mx);
        float wy2 = FSUB(va[j - 8].y, my);
        MAKEKEY(j, wx2, wy2, m, pk[j]);
    }
#pragma unroll
    for (int j = 0; j < 8; j++) va[j] = vlds[j + 8][tid];    // slots 16..23
#pragma unroll
    for (int j = 16; j < 24; j++) {
        int m = (mbits >> j) & 1u;
        float wx2 = FSUB(va[j - 16].x, mx);
        float wy2 = FSUB(va[j - 16].y, my);
        MAKEKEY(j, wx2, wy2, m, pk[j]);
    }

    // ---- phase 2.5: partial sort network — lowest 8 sorted into pk[0..7].
    // 97 CE, 2 VALU each; keys unique -> output order == extraction order.
    SORT8(0);
    SORT8(8);
    SORT8(16);
    MERGE_LOW8(8);
    MERGE_LOW8(16);

    // ---- phase 3: batch-issue the 8 dynamic gathers, then tree+walk ----
    float2 vi[8];
#pragma unroll
    for (int s = 0; s < 8; s++) {
        int ls = (int)(pk[s] & 31u) - 8;
        ls = ls < 0 ? 0 : ls;                // corner slots read row 0 (discarded)
        vi[s] = vlds[ls][tid];               // dynamic row: conflict-free
    }

    float firstx = 0.0f, firsty = 0.0f, prevx = 0.0f, prevy = 0.0f;
    float crs = 0.0f;
#pragma unroll
    for (int s = 0; s < 8; s++) {
        unsigned slot = pk[s] & 31u;
        float rxv, ryv;
        SELPAY(slot, vi[s], rxv, ryv);
        float gx = FSUB(rxv, mx);
        float gy = FSUB(ryv, my);
        bool act = s < k;                  // inactive pass: payload -> prev
        float bx = act ? gx : prevx;
        float by = act ? gy : prevy;
        if (s == 0) { firstx = bx; firsty = by; }
        else {
            // inactive: cross(prev,prev) = exact IEEE 0 (identical products)
            crs = FADD(crs, FSUB(FMUL(prevx, by), FMUL(prevy, bx)));
        }
        prevx = bx; prevy = by;
    }
    // rare tail: noise masks can push k past the geometric bound of 8.
    // Leftovers in pk[8..23] all exceed pk[7] -> successive minima continue
    // the ascending order; keys unique -> sentinel removal removes one.
    if (k > 8) {
        for (int s = 8; s < k; s++) {
            unsigned mn = pk[8];
#pragma unroll
            for (int j = 9; j < 24; j++) mn = (pk[j] < mn) ? pk[j] : mn;
            unsigned slot = mn & 31u;
            int ls = (int)slot - 8;
            ls = ls < 0 ? 0 : ls;
            float2 vt = vlds[ls][tid];
            float rxv, ryv;
            SELPAY(slot, vt, rxv, ryv);
            float bx = FSUB(rxv, mx);
            float by = FSUB(ryv, my);
            crs = FADD(crs, FSUB(FMUL(prevx, by), FMUL(prevy, bx)));
            prevx = bx; prevy = by;
#pragma unroll
            for (int j = 8; j < 24; j++) if (pk[j] == mn) pk[j] = 0xFFFFFFFFu;
        }
    }
    // close the ring
    crs = FADD(crs, FSUB(FMUL(prevx, firsty), FMUL(prevy, firstx)));
    float inter = FMUL(0.5f, fabsf(crs));

    float area1 = FMUL(pw, ph), area2 = FMUL(qw, qh);
    float uni = FSUB(FADD(area1, area2), inter);
    float iou = FMUL(inter, rcpf_(uni));

    out[i] = FADD(FSUB(1.0f, iou), FMUL(d2, rcpf_(c2d)));
}

extern "C" void kernel_launch(void* const* d_in, const int* in_sizes, int n_in,
                              void* d_out, int out_size, void* d_ws, size_t ws_size,
                              hipStream_t stream) {
    const float* pred = (const float*)d_in[0];
    const float* tgt  = (const float*)d_in[1];
    float* out = (float*)d_out;
    int n = in_sizes[0] / 6;
    int block = 256;
    int grid = (n + block - 1) / block;
    riou_kernel<<<grid, block, 0, stream>>>(pred, tgt, out, n);
}

// Round 7
// 110.501 us; speedup vs baseline: 1.0651x; 1.0343x over previous
//
#include <hip/hip_runtime.h>
#include <math.h>

// Round-18 = round-17 with the slot->row mapping bug fixed + sincosf
// reverted (isolate one change). r17 failed (absmax 4.3e5) because
// corners were stored at rows 16..23 / intersections at 0..15 while the
// phase-3 gather indexed vlds[slot] directly. Fix: row == slot.
//   rows 0..3  = c1 corners (slots 0..3)
//   rows 4..7  = c2 corners (slots 4..7)
//   rows 8..23 = intersections (slots 8..23)
// r17 rationale (unchanged): corners into LDS kill the SELPAY cndmask
// tree (~150 inst) and let corner regs die before the sort (no remat,
// small live set). LDS = [24][256] float2 = 48KB -> 12-wave/CU cap
// (~ measured occupancy of r16, so predicted neutral). Row stride 2048B
// == 0 mod 128 -> bank = f(lane) only -> conflict-free for dynamic rows;
// per-thread column -> no barriers.
// FROZEN (bit-critical): atan2f/cosf/sinf + __f*_rn corner chain, mask
// ratios, masked sx/sy sum order, centroid FDIV, key function, cross order.

#define FMUL __fmul_rn
#define FADD __fadd_rn
#define FSUB __fsub_rn
#define FDIV __fdiv_rn

__device__ __forceinline__ float rcpf_(float x) { return __builtin_amdgcn_rcpf(x); }

// compare-exchange on packed keys: min -> pk[A], max -> pk[B]
#define CE(A,B) do { unsigned _x = pk[A], _y = pk[B]; \
                     pk[A] = _x < _y ? _x : _y; pk[B] = _x < _y ? _y : _x; } while (0)

// Batcher odd-even mergesort of pk[o..o+7], 19 CE
#define SORT8(o) do { \
    CE(o+0,o+1); CE(o+2,o+3); CE(o+0,o+2); CE(o+1,o+3); CE(o+1,o+2); \
    CE(o+4,o+5); CE(o+6,o+7); CE(o+4,o+6); CE(o+5,o+7); CE(o+5,o+6); \
    CE(o+0,o+4); CE(o+1,o+5); CE(o+2,o+6); CE(o+3,o+7); \
    CE(o+2,o+4); CE(o+3,o+5); \
    CE(o+1,o+2); CE(o+3,o+4); CE(o+5,o+6); } while (0)

// pk[0..7] sorted asc, pk[o..o+7] sorted asc ->
// pk[0..7] = lowest 8 of the 16, sorted (half-cleaner + bitonic-8).
#define MERGE_LOW8(o) do { \
    CE(0,o+7); CE(1,o+6); CE(2,o+5); CE(3,o+4); \
    CE(4,o+3); CE(5,o+2); CE(6,o+1); CE(7,o+0); \
    CE(0,4); CE(1,5); CE(2,6); CE(3,7); \
    CE(0,2); CE(1,3); CE(4,6); CE(5,7); \
    CE(0,1); CE(2,3); CE(4,5); CE(6,7); } while (0)

// u32 packed key (27-bit diamond-angle | 5-bit slot), monotone in atan2.
#define MAKEKEY(J, WX, WY, M, DST) do {                                     \
    float _dsum = FADD(fabsf(WX), fabsf(WY));                               \
    float _rs = (_dsum > 0.0f) ? FMUL((WX), rcpf_(_dsum)) : 1.0f;           \
    float _keyf = copysignf(FSUB(1.0f, _rs), (WY));                         \
    unsigned _sbk = __float_as_uint(_keyf);                                 \
    unsigned _u = _sbk ^ (unsigned)(((int)_sbk >> 31) | (int)0x80000000);   \
    (DST) = (M) ? ((_u & 0xFFFFFFE0u) | (unsigned)(J))                      \
                : (0xFFFFFFE0u | (unsigned)(J));                            \
} while (0)

__global__
__attribute__((amdgpu_flat_work_group_size(256, 256), amdgpu_waves_per_eu(1)))
void riou_kernel(const float* __restrict__ pred,
                 const float* __restrict__ tgt,
                 float* __restrict__ out, int n)
{
    // row == slot: 0..3 c1 corners, 4..7 c2 corners, 8..23 intersections.
    __shared__ float2 vlds[24][256];
    const int tid = threadIdx.x;
    int i = blockIdx.x * blockDim.x + tid;
    if (i >= n) return;

    const float2* p2 = (const float2*)(pred + 6 * (size_t)i);
    const float2* q2 = (const float2*)(tgt  + 6 * (size_t)i);
    float2 pa = p2[0], pb = p2[1], pc2 = p2[2];
    float2 qa = q2[0], qb = q2[1], qc2 = q2[2];
    const float px = pa.x, py = pa.y, pw = pb.x, ph = pb.y;
    const float qx = qa.x, qy = qa.y, qw = qb.x, qh = qb.y;

    // bit-critical transcendental sequence — DO NOT substitute identities
    float rad1 = atan2f(pc2.x, pc2.y);
    float cA = cosf(rad1), sA = sinf(rad1);
    float rad2 = atan2f(qc2.x, qc2.y);
    float cB = cosf(rad2), sB = sinf(rad2);

    const float ddx[4] = {0.5f, -0.5f, -0.5f, 0.5f};
    const float ddy[4] = {0.5f, 0.5f, -0.5f, -0.5f};
    float c1x[4], c1y[4], c2x[4], c2y[4];
#pragma unroll
    for (int j = 0; j < 4; j++) {
        float cx = FMUL(ddx[j], pw), cy = FMUL(ddy[j], ph);
        c1x[j] = FADD(FSUB(FMUL(cx, cA), FMUL(cy, sA)), px);
        c1y[j] = FADD(FADD(FMUL(cx, sA), FMUL(cy, cA)), py);
        float dx2 = FMUL(ddx[j], qw), dy2 = FMUL(ddy[j], qh);
        c2x[j] = FADD(FSUB(FMUL(dx2, cB), FMUL(dy2, sB)), qx);
        c2y[j] = FADD(FADD(FMUL(dx2, sB), FMUL(dy2, cB)), qy);
        vlds[j][tid]     = make_float2(c1x[j], c1y[j]);   // slot j
        vlds[4 + j][tid] = make_float2(c2x[j], c2y[j]);   // slot 4+j
    }

    // enclosing-box diagonal + center distance
    float minx = c1x[0], maxx = c1x[0], miny = c1y[0], maxy = c1y[0];
#pragma unroll
    for (int j = 1; j < 4; j++) {
        minx = fminf(minx, c1x[j]); maxx = fmaxf(maxx, c1x[j]);
        miny = fminf(miny, c1y[j]); maxy = fmaxf(maxy, c1y[j]);
    }
#pragma unroll
    for (int j = 0; j < 4; j++) {
        minx = fminf(minx, c2x[j]); maxx = fmaxf(maxx, c2x[j]);
        miny = fminf(miny, c2y[j]); maxy = fmaxf(maxy, c2y[j]);
    }
    float wcb = FSUB(maxx, minx), hcb = FSUB(maxy, miny);
    float c2d = FADD(FMUL(wcb, wcb), FMUL(hcb, hcb));
    float dxc = FSUB(px, qx), dyc = FSUB(py, qy);
    float d2 = FADD(FMUL(dxc, dxc), FMUL(dyc, dyc));

    // ---- phase 1: 24 candidate slots, mask bits + masked sums ----
    unsigned mbits = 0;
    float sx = 0.0f, sy = 0.0f;
    const float eps = 1e-6f;
    const float hieps = 1.0f + 1e-6f;

    // slots 0-3: c1 corners inside c2
    {
        float ax = c2x[0], ay = c2y[0];
        float abx = FSUB(c2x[1], ax), aby = FSUB(c2y[1], ay);
        float adx = FSUB(c2x[3], ax), ady = FSUB(c2y[3], ay);
        float rab = rcpf_(FADD(FMUL(abx, abx), FMUL(aby, aby)));
        float rad = rcpf_(FADD(FMUL(adx, adx), FMUL(ady, ady)));
#pragma unroll
        for (int j = 0; j < 4; j++) {
            float amx = FSUB(c1x[j], ax), amy = FSUB(c1y[j], ay);
            float pab = FMUL(FADD(FMUL(abx, amx), FMUL(aby, amy)), rab);
            float pad = FMUL(FADD(FMUL(adx, amx), FMUL(ady, amy)), rad);
            int m = (pab > -eps) & (pab < hieps) & (pad > -eps) & (pad < hieps);
            mbits |= (unsigned)m << j;
            sx = FADD(sx, m ? c1x[j] : 0.0f);
            sy = FADD(sy, m ? c1y[j] : 0.0f);
        }
    }
    // slots 4-7: c2 corners inside c1
    {
        float ax = c1x[0], ay = c1y[0];
        float abx = FSUB(c1x[1], ax), aby = FSUB(c1y[1], ay);
        float adx = FSUB(c1x[3], ax), ady = FSUB(c1y[3], ay);
        float rab = rcpf_(FADD(FMUL(abx, abx), FMUL(aby, aby)));
        float rad = rcpf_(FADD(FMUL(adx, adx), FMUL(ady, ady)));
#pragma unroll
        for (int j = 0; j < 4; j++) {
            float amx = FSUB(c2x[j], ax), amy = FSUB(c2y[j], ay);
            float pab = FMUL(FADD(FMUL(abx, amx), FMUL(aby, amy)), rab);
            float pad = FMUL(FADD(FMUL(adx, amx), FMUL(ady, amy)), rad);
            int m = (pab > -eps) & (pab < hieps) & (pad > -eps) & (pad < hieps);
            mbits |= (unsigned)m << (4 + j);
            sx = FADD(sx, m ? c2x[j] : 0.0f);
            sy = FADD(sy, m ? c2y[j] : 0.0f);
        }
    }
    // slots 8-23: edge intersections; den_u = -den_t exactly -> one rcp.
    float fex[4], fey[4];
#pragma unroll
    for (int e2 = 0; e2 < 4; e2++) {
        fex[e2] = FSUB(c2x[(e2 + 1) & 3], c2x[e2]);
        fey[e2] = FSUB(c2y[(e2 + 1) & 3], c2y[e2]);
    }
#pragma unroll
    for (int e1 = 0; e1 < 4; e1++) {
        float x1 = c1x[e1], y1 = c1y[e1];
        float ex = FSUB(c1x[(e1 + 1) & 3], x1), ey = FSUB(c1y[(e1 + 1) & 3], y1);
#pragma unroll
        for (int e2 = 0; e2 < 4; e2++) {
            float dx31 = FSUB(c2x[e2], x1), dy31 = FSUB(c2y[e2], y1);
            float num_t = FSUB(FMUL(ex, dy31), FMUL(ey, dx31));
            float den_t = FSUB(FMUL(ey, fex[e2]), FMUL(ex, fey[e2]));
            float rd = rcpf_(den_t);          // den==0 -> inf -> masked below
            float tq = FMUL(num_t, rd);
            float num_u = FSUB(FMUL(fey[e2], dx31), FMUL(fex[e2], dy31));
            float uq = FMUL(num_u, rd);       // == -u exactly
            int m = (tq > 0.0f) & (tq < 1.0f) & (uq < 0.0f) & (uq > -1.0f);
            float ix = FADD(x1, FMUL(tq, ex));   // garbage if masked; gated
            float iy = FADD(y1, FMUL(tq, ey));
            int s = 4 * e1 + e2;
            vlds[8 + s][tid] = make_float2(ix, iy);   // slot 8+s == row 8+s
            mbits |= (unsigned)m << (8 + s);
            sx = FADD(sx, m ? ix : 0.0f);
            sy = FADD(sy, m ? iy : 0.0f);
        }
    }

    int k = __popc(mbits);

    // centroid (IEEE div: feeds every recentered coordinate — bit-frozen)
    float kk = (float)(k > 0 ? k : 1);
    float mx = FDIV(sx, kk), my = FDIV(sy, kk);

    // ---- phase 2: keys. Intersections read back in two batches of 8
    // (static rows -> immediate offsets, one lgkmcnt per batch); corner
    // keys (regs still live here) computed while batch A is in flight.
    unsigned pk[24];
    float2 va[8];
#pragma unroll
    for (int j = 0; j < 8; j++) va[j] = vlds[8 + j][tid];    // slots 8..15
#pragma unroll
    for (int j = 0; j < 8; j++) {                            // corners
        float rx = (j < 4) ? c1x[j] : c2x[j - 4];
        float ry = (j < 4) ? c1y[j] : c2y[j - 4];
        int m = (mbits >> j) & 1u;
        float wx2 = FSUB(rx, mx);
        float wy2 = FSUB(ry, my);
        MAKEKEY(j, wx2, wy2, m, pk[j]);
    }
#pragma unroll
    for (int j = 8; j < 16; j++) {                           // slots 8..15
        int m = (mbits >> j) & 1u;
        float wx2 = FSUB(va[j - 8].x, mx);
        float wy2 = FSUB(va[j - 8].y, my);
        MAKEKEY(j, wx2, wy2, m, pk[j]);
    }
#pragma unroll
    for (int j = 0; j < 8; j++) va[j] = vlds[16 + j][tid];   // slots 16..23
#pragma unroll
    for (int j = 16; j < 24; j++) {
        int m = (mbits >> j) & 1u;
        float wx2 = FSUB(va[j - 16].x, mx);
        float wy2 = FSUB(va[j - 16].y, my);
        MAKEKEY(j, wx2, wy2, m, pk[j]);
    }
    // corner registers DIE here -> small live set across the sort.

    // ---- phase 2.5: partial sort network — lowest 8 sorted into pk[0..7].
    // 97 CE, 2 VALU each; keys unique -> output order == extraction order.
    SORT8(0);
    SORT8(8);
    SORT8(16);
    MERGE_LOW8(8);
    MERGE_LOW8(16);

    // ---- phase 3: batch-issue 8 dynamic gathers (row == slot), walk ----
    float2 vi[8];
#pragma unroll
    for (int s = 0; s < 8; s++) {
        unsigned row = pk[s] & 31u;          // in [0,24): row == slot
        vi[s] = vlds[row][tid];              // dynamic row: conflict-free
    }

    float firstx = 0.0f, firsty = 0.0f, prevx = 0.0f, prevy = 0.0f;
    float crs = 0.0f;
#pragma unroll
    for (int s = 0; s < 8; s++) {
        float gx = FSUB(vi[s].x, mx);
        float gy = FSUB(vi[s].y, my);
        bool act = s < k;                  // inactive pass: payload -> prev
        float bx = act ? gx : prevx;
        float by = act ? gy : prevy;
        if (s == 0) { firstx = bx; firsty = by; }
        else {
            // inactive: cross(prev,prev) = exact IEEE 0 (identical products)
            crs = FADD(crs, FSUB(FMUL(prevx, by), FMUL(prevy, bx)));
        }
        prevx = bx; prevy = by;
    }
    // rare tail: noise masks can push k past the geometric bound of 8.
    // Leftovers in pk[8..23] all exceed pk[7] -> successive minima continue
    // the ascending order; keys unique -> sentinel removal removes one.
    if (k > 8) {
        for (int s = 8; s < k; s++) {
            unsigned mn = pk[8];
#pragma unroll
            for (int j = 9; j < 24; j++) mn = (pk[j] < mn) ? pk[j] : mn;
            float2 vt = vlds[mn & 31u][tid];
            float bx = FSUB(vt.x, mx);
            float by = FSUB(vt.y, my);
            crs = FADD(crs, FSUB(FMUL(prevx, by), FMUL(prevy, bx)));
            prevx = bx; prevy = by;
#pragma unroll
            for (int j = 8; j < 24; j++) if (pk[j] == mn) pk[j] = 0xFFFFFFFFu;
        }
    }
    // close the ring
    crs = FADD(crs, FSUB(FMUL(prevx, firsty), FMUL(prevy, firstx)));
    float inter = FMUL(0.5f, fabsf(crs));

    float area1 = FMUL(pw, ph), area2 = FMUL(qw, qh);
    float uni = FSUB(FADD(area1, area2), inter);
    float iou = FMUL(inter, rcpf_(uni));

    out[i] = FADD(FSUB(1.0f, iou), FMUL(d2, rcpf_(c2d)));
}

extern "C" void kernel_launch(void* const* d_in, const int* in_sizes, int n_in,
                              void* d_out, int out_size, void* d_ws, size_t ws_size,
                              hipStream_t stream) {
    const float* pred = (const float*)d_in[0];
    const float* tgt  = (const float*)d_in[1];
    float* out = (float*)d_out;
    int n = in_sizes[0] / 6;
    int block = 256;
    int grid = (n + block - 1) / block;
    riou_kernel<<<grid, block, 0, stream>>>(pred, tgt, out, n);
}